// Round 4
// baseline (133.864 us; speedup 1.0000x reference)
//
#include <hip/hip_runtime.h>
#include <hip/hip_bf16.h>
#include <math.h>

#define D_MODEL 256
#define EXPERT_DIM 512
#define NUM_EXPERTS 8
#define T_TOKENS 4096
#define TM 32
#define XS_LD 264    // 256+8 bf16 pad: 528B row, bank-group stride 4 (measured 0 conflicts)
#define HS_LD 136    // 128+8 bf16 pad: 272B row, same stride-4 banking

typedef unsigned short ushort_t;
typedef short short8_t __attribute__((ext_vector_type(8)));
typedef float f32x4 __attribute__((ext_vector_type(4)));

__device__ __forceinline__ ushort_t f2bf(float f) {
    unsigned int u = __float_as_uint(f);
    u += 0x7FFFu + ((u >> 16) & 1u);   // round-to-nearest-even
    return (ushort_t)(u >> 16);
}

// ---------------------------------------------------------------------------
// Zero out (1M floats) + counts in one dispatch (replaces two fills).
// ---------------------------------------------------------------------------
__global__ __launch_bounds__(256) void zero_kernel(float* __restrict__ out,
                                                   int* __restrict__ counts)
{
    int i = blockIdx.x * 256 + threadIdx.x;
    *(float4*)(out + (size_t)i * 4) = make_float4(0.f, 0.f, 0.f, 0.f);
    if (i < NUM_EXPERTS) counts[i] = 0;
}

// ---------------------------------------------------------------------------
// Fused prep: blocks 0..15 = gate (LDS-staged coalesced x reads, LDS
// histogram -> 8 global atomics/block), blocks 16..1039 = weight convert
// fp32 -> bf16 MFMA-fragment order.
// W1f: [e][ntile(32)][ks(8)][lane(64)][8]   (ntile = q*8 + w*2 + nt)
// W2f: [e][q(4)][ntile(16)][ks(4)][lane(64)][8]
// ---------------------------------------------------------------------------
__global__ __launch_bounds__(256) void prep_kernel(
    const float* __restrict__ x, const float* __restrict__ Wg,
    const float* __restrict__ bg, const float* __restrict__ bias,
    const float* __restrict__ W1, const float* __restrict__ W2,
    ushort_t* __restrict__ W1f, ushort_t* __restrict__ W2f,
    int* __restrict__ counts, int* __restrict__ lists, float* __restrict__ wts)
{
    __shared__ float xs[256][33];   // gate staging; pad 33 -> 2-way max (free)
    __shared__ int lcount[NUM_EXPERTS];
    __shared__ int lbase[NUM_EXPERTS];

    const int tid = threadIdx.x;
    if (blockIdx.x < 16) {
        // ---------------- gate role ----------------
        const int tbase = blockIdx.x * 256;
        if (tid < NUM_EXPERTS) lcount[tid] = 0;
        float acc[NUM_EXPERTS];
#pragma unroll
        for (int e = 0; e < NUM_EXPERTS; ++e) acc[e] = 0.f;

        for (int kc = 0; kc < 8; ++kc) {
            __syncthreads();
#pragma unroll
            for (int it = 0; it < 8; ++it) {
                int pos = it * 256 + tid;
                int tl = pos >> 3, c4 = pos & 7;
                float4 v = *(const float4*)(x + (size_t)(tbase + tl) * D_MODEL
                                            + kc * 32 + c4 * 4);
                xs[tl][c4 * 4 + 0] = v.x; xs[tl][c4 * 4 + 1] = v.y;
                xs[tl][c4 * 4 + 2] = v.z; xs[tl][c4 * 4 + 3] = v.w;
            }
            __syncthreads();
            for (int k = 0; k < 32; ++k) {
                float xv = xs[tid][k];
                const float* wr = Wg + (kc * 32 + k) * NUM_EXPERTS; // uniform -> scalar
#pragma unroll
                for (int e = 0; e < NUM_EXPERTS; ++e) acc[e] += xv * wr[e];
            }
        }
        float v0 = -3.0e38f, v1 = -3.0e38f; int i0 = 0, i1 = 0;
#pragma unroll
        for (int e = 0; e < NUM_EXPERTS; ++e) {
            float v = acc[e] + bg[e] + bias[e];
            if (v > v0) { v1 = v0; i1 = i0; v0 = v; i0 = e; }
            else if (v > v1) { v1 = v; i1 = e; }
        }
        float e1 = __expf(v1 - v0);
        float inv = 1.f / (1.f + e1);
        float w0 = inv, w1 = e1 * inv;

        int p0 = atomicAdd(&lcount[i0], 1);    // LDS atomics
        int p1 = atomicAdd(&lcount[i1], 1);
        __syncthreads();
        if (tid < NUM_EXPERTS) lbase[tid] = atomicAdd(&counts[tid], lcount[tid]);
        __syncthreads();
        int t = tbase + tid;
        int q0 = lbase[i0] + p0;
        int q1 = lbase[i1] + p1;
        lists[i0 * T_TOKENS + q0] = t;  wts[i0 * T_TOKENS + q0] = w0;
        lists[i1 * T_TOKENS + q1] = t;  wts[i1 * T_TOKENS + q1] = w1;
    } else {
        // ---------------- convert role ----------------
        int gid = (blockIdx.x - 16) * 256 + tid;    // 0 .. 262143
        bool isW2 = gid >= 131072;
        int idx = isW2 ? gid - 131072 : gid;
        int lane = idx & 63;
        int l15 = lane & 15, quad = lane >> 4;
        ushort_t o[8];
        if (!isW2) {
            int ks = (idx >> 6) & 7;
            int ntile = (idx >> 9) & 31, e = idx >> 14;
            int nn = ntile * 16 + l15;
            int k0 = ks * 32 + quad * 8;
            const float* s = W1 + ((size_t)e * D_MODEL + k0) * EXPERT_DIM + nn;
#pragma unroll
            for (int j = 0; j < 8; ++j) o[j] = f2bf(s[j * EXPERT_DIM]);
            *(int4*)(W1f + (size_t)idx * 8) = *(int4*)o;
        } else {
            int ks = (idx >> 6) & 3;
            int ntile = (idx >> 8) & 15;
            int q = (idx >> 12) & 3, e = idx >> 14;
            int nn = ntile * 16 + l15;
            int k0 = q * 128 + ks * 32 + quad * 8;
            const float* s = W2 + ((size_t)e * EXPERT_DIM + k0) * D_MODEL + nn;
#pragma unroll
            for (int j = 0; j < 8; ++j) o[j] = f2bf(s[j * D_MODEL]);
            *(int4*)(W2f + (size_t)idx * 8) = *(int4*)o;
        }
    }
}

// ---------------------------------------------------------------------------
// Expert FFN, bf16 MFMA. grid (expert, q-slice(4), tile), block 256 = 4 waves.
// Each block: 128-wide slice of EXPERT_DIM. stage1 H_q = relu(X@W1[:,q]+b1_q);
// stage2 partial Y = H_q @ W2[q rows,:]; out[tok] += w*(Y + (q==0? b2:0)).
// B-frags: contiguous wave-loads from fragment-ordered weights, double-
// buffered; stage-1 B prefetched before gather barrier, stage-2 B before
// the Hs barrier. LDS ~26 KB.
// ---------------------------------------------------------------------------
__global__ __launch_bounds__(256) void moe_expert_mfma(
    const float* __restrict__ x,
    const ushort_t* __restrict__ W1f, const float* __restrict__ b1,
    const ushort_t* __restrict__ W2f, const float* __restrict__ b2,
    const int* __restrict__ counts, const int* __restrict__ lists,
    const float* __restrict__ wts, float* __restrict__ out)
{
    const int e = blockIdx.x;
    const int q = blockIdx.y;
    const int n = counts[e];
    const int base = blockIdx.z * TM;
    if (base >= n) return;
    const int m = min(TM, n - base);

    __shared__ ushort_t Xs[TM * XS_LD];   // 16.5 KB
    __shared__ ushort_t Hs[TM * HS_LD];   // 8.5 KB
    __shared__ int   toks[TM];
    __shared__ float wt_s[TM];

    const int tid = threadIdx.x;
    const int lane = tid & 63;
    const int w = tid >> 6;
    const int l15 = lane & 15;
    const int quad = lane >> 4;

    // stage-1 B prefetch, independent of LDS -> issue before gather barrier
    const ushort_t* W1p = W1f + (size_t)(e * 32 + q * 8 + w * 2) * 4096 + lane * 8;
    short8_t bc[2];
    bc[0] = *(const short8_t*)(W1p);
    bc[1] = *(const short8_t*)(W1p + 4096);

    if (tid < TM) {
        const int* lst = lists + e * T_TOKENS + base;
        const float* wr = wts + e * T_TOKENS + base;
        toks[tid] = (tid < m) ? lst[tid] : -1;
        wt_s[tid] = (tid < m) ? wr[tid] : 0.f;
    }
    __syncthreads();

    // gather X tile: fp32 -> bf16 inline
    for (int c = tid; c < TM * 32; c += 256) {
        int r = c >> 5, c8 = c & 31;
        int tk = toks[r];
        ushort_t o[8];
        if (tk >= 0) {
            const float* src = x + (size_t)tk * D_MODEL + c8 * 8;
            float4 v0 = *(const float4*)src;
            float4 v1 = *(const float4*)(src + 4);
            o[0] = f2bf(v0.x); o[1] = f2bf(v0.y); o[2] = f2bf(v0.z); o[3] = f2bf(v0.w);
            o[4] = f2bf(v1.x); o[5] = f2bf(v1.y); o[6] = f2bf(v1.z); o[7] = f2bf(v1.w);
        } else {
#pragma unroll
            for (int j = 0; j < 8; ++j) o[j] = 0;
        }
        *(int4*)(Xs + r * XS_LD + c8 * 8) = *(int4*)o;
    }
    __syncthreads();

    // ---------------- stage 1: H_q = relu(X @ W1[:, q*128..] + b1) ---------
    float b1v[2];
#pragma unroll
    for (int nt = 0; nt < 2; ++nt)
        b1v[nt] = b1[e * EXPERT_DIM + (q * 8 + w * 2 + nt) * 16 + l15];

    f32x4 acc1[2][2] = {};
    for (int ks = 0; ks < 8; ++ks) {
        short8_t bn[2];
        if (ks < 7) {
            bn[0] = *(const short8_t*)(W1p + (ks + 1) * 512);
            bn[1] = *(const short8_t*)(W1p + 4096 + (ks + 1) * 512);
        }
        short8_t a0 = *(const short8_t*)(Xs + l15 * XS_LD + ks * 32 + quad * 8);
        short8_t a1 = *(const short8_t*)(Xs + (16 + l15) * XS_LD + ks * 32 + quad * 8);
#pragma unroll
        for (int nt = 0; nt < 2; ++nt) {
            acc1[0][nt] = __builtin_amdgcn_mfma_f32_16x16x32_bf16(a0, bc[nt], acc1[0][nt], 0, 0, 0);
            acc1[1][nt] = __builtin_amdgcn_mfma_f32_16x16x32_bf16(a1, bc[nt], acc1[1][nt], 0, 0, 0);
        }
        if (ks < 7) { bc[0] = bn[0]; bc[1] = bn[1]; }
    }

    // stage-2 B prefetch before the Hs round-trip barrier
    const ushort_t* W2p = W2f + (size_t)((e * 4 + q) * 16 + w * 4) * 2048 + lane * 8;
    short8_t bc2[4];
#pragma unroll
    for (int nt = 0; nt < 4; ++nt) bc2[nt] = *(const short8_t*)(W2p + nt * 2048);
    float b2v[4];
#pragma unroll
    for (int nt = 0; nt < 4; ++nt)
        b2v[nt] = (q == 0) ? b2[e * D_MODEL + w * 64 + nt * 16 + l15] : 0.f;

    // relu + bias -> Hs (bf16, 128 cols)
#pragma unroll
    for (int mt = 0; mt < 2; ++mt)
#pragma unroll
        for (int nt = 0; nt < 2; ++nt)
#pragma unroll
            for (int r = 0; r < 4; ++r) {
                int row = mt * 16 + quad * 4 + r;
                int col = w * 32 + nt * 16 + l15;
                float h = fmaxf(acc1[mt][nt][r] + b1v[nt], 0.f);
                Hs[row * HS_LD + col] = f2bf(h);
            }
    __syncthreads();

    // ---------------- stage 2: Y += H_q @ W2[q rows, :] --------------------
    f32x4 acc2[2][4] = {};
    for (int ks = 0; ks < 4; ++ks) {
        short8_t bn2[4];
        if (ks < 3) {
#pragma unroll
            for (int nt = 0; nt < 4; ++nt)
                bn2[nt] = *(const short8_t*)(W2p + nt * 2048 + (ks + 1) * 512);
        }
        short8_t a0 = *(const short8_t*)(Hs + l15 * HS_LD + ks * 32 + quad * 8);
        short8_t a1 = *(const short8_t*)(Hs + (16 + l15) * HS_LD + ks * 32 + quad * 8);
#pragma unroll
        for (int nt = 0; nt < 4; ++nt) {
            acc2[0][nt] = __builtin_amdgcn_mfma_f32_16x16x32_bf16(a0, bc2[nt], acc2[0][nt], 0, 0, 0);
            acc2[1][nt] = __builtin_amdgcn_mfma_f32_16x16x32_bf16(a1, bc2[nt], acc2[1][nt], 0, 0, 0);
        }
        if (ks < 3) {
#pragma unroll
            for (int nt = 0; nt < 4; ++nt) bc2[nt] = bn2[nt];
        }
    }

    // epilogue: out[tok] += w * (y_partial + b2_term)
#pragma unroll
    for (int mt = 0; mt < 2; ++mt)
#pragma unroll
        for (int nt = 0; nt < 4; ++nt)
#pragma unroll
            for (int r = 0; r < 4; ++r) {
                int row = mt * 16 + quad * 4 + r;
                int tk = toks[row];
                if (tk >= 0) {
                    int col = w * 64 + nt * 16 + l15;
                    atomicAdd(&out[(size_t)tk * D_MODEL + col],
                              wt_s[row] * (acc2[mt][nt][r] + b2v[nt]));
                }
            }
}

extern "C" void kernel_launch(void* const* d_in, const int* in_sizes, int n_in,
                              void* d_out, int out_size, void* d_ws, size_t ws_size,
                              hipStream_t stream)
{
    const float* x    = (const float*)d_in[0];
    const float* Wg   = (const float*)d_in[1];
    const float* bg   = (const float*)d_in[2];
    const float* bias = (const float*)d_in[3];
    const float* W1   = (const float*)d_in[4];
    const float* b1   = (const float*)d_in[5];
    const float* W2   = (const float*)d_in[6];
    const float* b2   = (const float*)d_in[7];
    float* out = (float*)d_out;

    // workspace layout
    char* ws = (char*)d_ws;
    int*      counts = (int*)ws;                                   // 256 B
    int*      lists  = (int*)(ws + 256);                           // 128 KB
    float*    wts    = (float*)(ws + 256 + 131072);                // 128 KB
    ushort_t* W1f    = (ushort_t*)(ws + 256 + 262144);             // 2 MB
    ushort_t* W2f    = (ushort_t*)(ws + 256 + 262144 + 2097152);   // 2 MB

    zero_kernel<<<1024, 256, 0, stream>>>(out, counts);

    prep_kernel<<<1040, 256, 0, stream>>>(
        x, Wg, bg, bias, W1, W2, W1f, W2f, counts, lists, wts);

    moe_expert_mfma<<<dim3(NUM_EXPERTS, 4, T_TOKENS / TM), 256, 0, stream>>>(
        x, W1f, b1, W2f, b2, counts, lists, wts, out);
}

// Round 5
// 117.163 us; speedup vs baseline: 1.1425x; 1.1425x over previous
//
#include <hip/hip_runtime.h>
#include <hip/hip_bf16.h>
#include <math.h>

#define D_MODEL 256
#define EXPERT_DIM 512
#define NUM_EXPERTS 8
#define T_TOKENS 4096
#define TM 32
#define XS_LD 264    // 256+8 bf16 pad: 528B row (measured 0 conflicts)

typedef unsigned short ushort_t;
typedef short short8_t __attribute__((ext_vector_type(8)));
typedef float f32x4 __attribute__((ext_vector_type(4)));

__device__ __forceinline__ ushort_t f2bf(float f) {
    unsigned int u = __float_as_uint(f);
    u += 0x7FFFu + ((u >> 16) & 1u);   // round-to-nearest-even
    return (ushort_t)(u >> 16);
}

// ---------------------------------------------------------------------------
// Zero the 8 expert counts (ws is poisoned 0xAA before every timed call).
// ---------------------------------------------------------------------------
__global__ void zero_counts_kernel(int* __restrict__ counts)
{
    if (threadIdx.x < NUM_EXPERTS) counts[threadIdx.x] = 0;
}

// ---------------------------------------------------------------------------
// Fused prep: blocks 0..15 = gate (coalesced LDS-staged x reads, LDS
// histogram -> 8 global atomics/block, writes lists/wts/slots), blocks
// 16..1039 = weight convert fp32 -> bf16 MFMA-fragment order.
// W1f: idx = e<<14 | ntile(5b)<<9 | ks(3b)<<6 | lane   (8 bf16 elems each)
//      element (k,n): n = ntile*16 + (lane&15), k = ks*32 + (lane>>4)*8 + j
// W2f: idx = e<<14 | half<<13 | ntile(4b)<<9 | ks(3b)<<6 | lane
//      element (k,n): n = ntile*16 + l15, k = half*256 + ks*32 + quad*8 + j
// ---------------------------------------------------------------------------
__global__ __launch_bounds__(256) void prep_kernel(
    const float* __restrict__ x, const float* __restrict__ Wg,
    const float* __restrict__ bg, const float* __restrict__ bias,
    const float* __restrict__ W1, const float* __restrict__ W2,
    ushort_t* __restrict__ W1f, ushort_t* __restrict__ W2f,
    int* __restrict__ counts, int* __restrict__ lists,
    float* __restrict__ wts, int* __restrict__ slots)
{
    __shared__ float xs[256][33];
    __shared__ int lcount[NUM_EXPERTS];
    __shared__ int lbase[NUM_EXPERTS];

    const int tid = threadIdx.x;
    if (blockIdx.x < 16) {
        // ---------------- gate role ----------------
        const int tbase = blockIdx.x * 256;
        if (tid < NUM_EXPERTS) lcount[tid] = 0;
        float acc[NUM_EXPERTS];
#pragma unroll
        for (int e = 0; e < NUM_EXPERTS; ++e) acc[e] = 0.f;

        for (int kc = 0; kc < 8; ++kc) {
            __syncthreads();
#pragma unroll
            for (int it = 0; it < 8; ++it) {
                int pos = it * 256 + tid;
                int tl = pos >> 3, c4 = pos & 7;
                float4 v = *(const float4*)(x + (size_t)(tbase + tl) * D_MODEL
                                            + kc * 32 + c4 * 4);
                xs[tl][c4 * 4 + 0] = v.x; xs[tl][c4 * 4 + 1] = v.y;
                xs[tl][c4 * 4 + 2] = v.z; xs[tl][c4 * 4 + 3] = v.w;
            }
            __syncthreads();
            for (int k = 0; k < 32; ++k) {
                float xv = xs[tid][k];
                const float* wr = Wg + (kc * 32 + k) * NUM_EXPERTS;
#pragma unroll
                for (int e = 0; e < NUM_EXPERTS; ++e) acc[e] += xv * wr[e];
            }
        }
        float v0 = -3.0e38f, v1 = -3.0e38f; int i0 = 0, i1 = 0;
#pragma unroll
        for (int e = 0; e < NUM_EXPERTS; ++e) {
            float v = acc[e] + bg[e] + bias[e];
            if (v > v0) { v1 = v0; i1 = i0; v0 = v; i0 = e; }
            else if (v > v1) { v1 = v; i1 = e; }
        }
        float e1 = __expf(v1 - v0);
        float inv = 1.f / (1.f + e1);
        float w0 = inv, w1 = e1 * inv;

        int p0 = atomicAdd(&lcount[i0], 1);    // LDS atomics
        int p1 = atomicAdd(&lcount[i1], 1);
        __syncthreads();
        if (tid < NUM_EXPERTS) lbase[tid] = atomicAdd(&counts[tid], lcount[tid]);
        __syncthreads();
        int t = tbase + tid;
        int q0 = lbase[i0] + p0;
        int q1 = lbase[i1] + p1;
        lists[i0 * T_TOKENS + q0] = t;  wts[i0 * T_TOKENS + q0] = w0;
        lists[i1 * T_TOKENS + q1] = t;  wts[i1 * T_TOKENS + q1] = w1;
        slots[t * 2 + 0] = i0 * T_TOKENS + q0;
        slots[t * 2 + 1] = i1 * T_TOKENS + q1;
    } else {
        // ---------------- convert role ----------------
        int gid = (blockIdx.x - 16) * 256 + tid;    // 0 .. 262143
        bool isW2 = gid >= 131072;
        int idx = isW2 ? gid - 131072 : gid;
        int lane = idx & 63;
        int l15 = lane & 15, quad = lane >> 4;
        int ks = (idx >> 6) & 7;
        ushort_t o[8];
        if (!isW2) {
            int ntile = (idx >> 9) & 31, e = idx >> 14;
            int nn = ntile * 16 + l15;
            int k0 = ks * 32 + quad * 8;
            const float* s = W1 + ((size_t)e * D_MODEL + k0) * EXPERT_DIM + nn;
#pragma unroll
            for (int j = 0; j < 8; ++j) o[j] = f2bf(s[j * EXPERT_DIM]);
            *(int4*)(W1f + (size_t)idx * 8) = *(int4*)o;
        } else {
            int ntile = (idx >> 9) & 15, half = (idx >> 13) & 1, e = idx >> 14;
            int nn = ntile * 16 + l15;
            int k0 = half * 256 + ks * 32 + quad * 8;
            const float* s = W2 + ((size_t)e * EXPERT_DIM + k0) * D_MODEL + nn;
#pragma unroll
            for (int j = 0; j < 8; ++j) o[j] = f2bf(s[j * D_MODEL]);
            *(int4*)(W2f + (size_t)idx * 8) = *(int4*)o;
        }
    }
}

// ---------------------------------------------------------------------------
// Expert FFN, bf16 MFMA. grid (expert, half, tile), block 256 = 4 waves.
// Each block: 256-wide half of EXPERT_DIM. stage1 H = relu(X@W1[:,half]+b1);
// stage2 Y_partial = H @ W2[half rows,:]. Epilogue: PLAIN coalesced stores of
// w*(Y_partial + (half? b2:0)) into ybuf[(half*8+e)*4096 + pos] — no atomics
// (was ~4-8M device atomic dwords = the r3/r4 stall). B-frags are contiguous
// wave-loads from fragment-ordered weights, double-buffered. LDS 33 KB.
// ---------------------------------------------------------------------------
__global__ __launch_bounds__(256) void moe_expert_mfma(
    const float* __restrict__ x,
    const ushort_t* __restrict__ W1f, const float* __restrict__ b1,
    const ushort_t* __restrict__ W2f, const float* __restrict__ b2,
    const int* __restrict__ counts, const int* __restrict__ lists,
    const float* __restrict__ wts, float* __restrict__ ybuf)
{
    const int e = blockIdx.x;
    const int half = blockIdx.y;
    const int n = counts[e];
    const int base = blockIdx.z * TM;
    if (base >= n) return;
    const int m = min(TM, n - base);

    __shared__ ushort_t Xs[TM * XS_LD];   // 16.5 KB
    __shared__ ushort_t Hs[TM * XS_LD];   // 16.5 KB (256 cols used)
    __shared__ int   toks[TM];
    __shared__ float wt_s[TM];

    const int tid = threadIdx.x;
    const int lane = tid & 63;
    const int w = tid >> 6;        // wave id: 64-col quarter of this half
    const int l15 = lane & 15;
    const int quad = lane >> 4;

    // stage-1 B prefetch (independent of LDS) before the gather barrier
    const ushort_t* W1p = W1f + (size_t)(e * 32 + half * 16 + w * 4) * 4096 + lane * 8;
    short8_t bc[4];
#pragma unroll
    for (int nt = 0; nt < 4; ++nt) bc[nt] = *(const short8_t*)(W1p + nt * 4096);

    if (tid < TM) {
        const int* lst = lists + e * T_TOKENS + base;
        const float* wr = wts + e * T_TOKENS + base;
        toks[tid] = (tid < m) ? lst[tid] : -1;
        wt_s[tid] = (tid < m) ? wr[tid] : 0.f;
    }
    __syncthreads();

    // gather X tile: fp32 -> bf16 inline, coalesced 1KB-row reads
    for (int c = tid; c < TM * 32; c += 256) {
        int r = c >> 5, c8 = c & 31;
        int tk = toks[r];
        ushort_t o[8];
        if (tk >= 0) {
            const float* src = x + (size_t)tk * D_MODEL + c8 * 8;
            float4 v0 = *(const float4*)src;
            float4 v1 = *(const float4*)(src + 4);
            o[0] = f2bf(v0.x); o[1] = f2bf(v0.y); o[2] = f2bf(v0.z); o[3] = f2bf(v0.w);
            o[4] = f2bf(v1.x); o[5] = f2bf(v1.y); o[6] = f2bf(v1.z); o[7] = f2bf(v1.w);
        } else {
#pragma unroll
            for (int j = 0; j < 8; ++j) o[j] = 0;
        }
        *(int4*)(Xs + r * XS_LD + c8 * 8) = *(int4*)o;
    }
    __syncthreads();

    // ---------------- stage 1: H = relu(X @ W1[:, half] + b1) --------------
    float b1v[4];
#pragma unroll
    for (int nt = 0; nt < 4; ++nt)
        b1v[nt] = b1[e * EXPERT_DIM + half * 256 + w * 64 + nt * 16 + l15];

    f32x4 acc1[2][4] = {};
    for (int ks = 0; ks < 8; ++ks) {
        short8_t bn[4];
        if (ks < 7) {
#pragma unroll
            for (int nt = 0; nt < 4; ++nt)
                bn[nt] = *(const short8_t*)(W1p + nt * 4096 + (ks + 1) * 512);
        }
        short8_t a0 = *(const short8_t*)(Xs + l15 * XS_LD + ks * 32 + quad * 8);
        short8_t a1 = *(const short8_t*)(Xs + (16 + l15) * XS_LD + ks * 32 + quad * 8);
#pragma unroll
        for (int nt = 0; nt < 4; ++nt) {
            acc1[0][nt] = __builtin_amdgcn_mfma_f32_16x16x32_bf16(a0, bc[nt], acc1[0][nt], 0, 0, 0);
            acc1[1][nt] = __builtin_amdgcn_mfma_f32_16x16x32_bf16(a1, bc[nt], acc1[1][nt], 0, 0, 0);
        }
        if (ks < 7) {
#pragma unroll
            for (int nt = 0; nt < 4; ++nt) bc[nt] = bn[nt];
        }
    }

    // stage-2 B prefetch before the Hs round-trip barrier
    const ushort_t* W2p = W2f + (size_t)((e * 2 + half) * 16 + w * 4) * 4096 + lane * 8;
    short8_t bc2[4];
#pragma unroll
    for (int nt = 0; nt < 4; ++nt) bc2[nt] = *(const short8_t*)(W2p + nt * 4096);
    float b2v[4];
#pragma unroll
    for (int nt = 0; nt < 4; ++nt)
        b2v[nt] = half ? b2[e * D_MODEL + w * 64 + nt * 16 + l15] : 0.f;

    // relu + bias -> Hs (bf16, 256 cols of this half)
#pragma unroll
    for (int mt = 0; mt < 2; ++mt)
#pragma unroll
        for (int nt = 0; nt < 4; ++nt)
#pragma unroll
            for (int r = 0; r < 4; ++r) {
                int row = mt * 16 + quad * 4 + r;
                int col = w * 64 + nt * 16 + l15;
                float h = fmaxf(acc1[mt][nt][r] + b1v[nt], 0.f);
                Hs[row * XS_LD + col] = f2bf(h);
            }
    __syncthreads();

    // ---------------- stage 2: Y = H @ W2[half rows, :] --------------------
    f32x4 acc2[2][4] = {};
    for (int ks = 0; ks < 8; ++ks) {
        short8_t bn2[4];
        if (ks < 7) {
#pragma unroll
            for (int nt = 0; nt < 4; ++nt)
                bn2[nt] = *(const short8_t*)(W2p + nt * 4096 + (ks + 1) * 512);
        }
        short8_t a0 = *(const short8_t*)(Hs + l15 * XS_LD + ks * 32 + quad * 8);
        short8_t a1 = *(const short8_t*)(Hs + (16 + l15) * XS_LD + ks * 32 + quad * 8);
#pragma unroll
        for (int nt = 0; nt < 4; ++nt) {
            acc2[0][nt] = __builtin_amdgcn_mfma_f32_16x16x32_bf16(a0, bc2[nt], acc2[0][nt], 0, 0, 0);
            acc2[1][nt] = __builtin_amdgcn_mfma_f32_16x16x32_bf16(a1, bc2[nt], acc2[1][nt], 0, 0, 0);
        }
        if (ks < 7) {
#pragma unroll
            for (int nt = 0; nt < 4; ++nt) bc2[nt] = bn2[nt];
        }
    }

    // epilogue: plain coalesced stores into ybuf row (half*8+e)*4096 + pos
    float* yrow = ybuf + ((size_t)(half * NUM_EXPERTS + e) * T_TOKENS + base) * D_MODEL;
#pragma unroll
    for (int mt = 0; mt < 2; ++mt)
#pragma unroll
        for (int nt = 0; nt < 4; ++nt)
#pragma unroll
            for (int r = 0; r < 4; ++r) {
                int row = mt * 16 + quad * 4 + r;
                if (row < m) {
                    int col = w * 64 + nt * 16 + l15;
                    yrow[(size_t)row * D_MODEL + col] =
                        wt_s[row] * (acc2[mt][nt][r] + b2v[nt]);
                }
            }
}

// ---------------------------------------------------------------------------
// Combine: out[t] = sum of the 4 ybuf rows for token t (2 experts x 2 halves).
// One wave per token: 4 x 1KB coalesced row reads + 1KB store.
// ---------------------------------------------------------------------------
__global__ __launch_bounds__(256) void combine_kernel(
    const int* __restrict__ slots, const float* __restrict__ ybuf,
    float* __restrict__ out)
{
    int gid = blockIdx.x * 256 + threadIdx.x;   // T_TOKENS * 64 threads
    int t = gid >> 6, lane = gid & 63;
    int s0 = slots[t * 2 + 0];
    int s1 = slots[t * 2 + 1];
    const size_t H = (size_t)NUM_EXPERTS * T_TOKENS * D_MODEL;  // half-bank stride
    float4 a = ((const float4*)(ybuf + (size_t)s0 * D_MODEL))[lane];
    float4 b = ((const float4*)(ybuf + (size_t)s0 * D_MODEL + H))[lane];
    float4 c = ((const float4*)(ybuf + (size_t)s1 * D_MODEL))[lane];
    float4 d = ((const float4*)(ybuf + (size_t)s1 * D_MODEL + H))[lane];
    float4 r;
    r.x = a.x + b.x + c.x + d.x;
    r.y = a.y + b.y + c.y + d.y;
    r.z = a.z + b.z + c.z + d.z;
    r.w = a.w + b.w + c.w + d.w;
    ((float4*)(out + (size_t)t * D_MODEL))[lane] = r;
}

extern "C" void kernel_launch(void* const* d_in, const int* in_sizes, int n_in,
                              void* d_out, int out_size, void* d_ws, size_t ws_size,
                              hipStream_t stream)
{
    const float* x    = (const float*)d_in[0];
    const float* Wg   = (const float*)d_in[1];
    const float* bg   = (const float*)d_in[2];
    const float* bias = (const float*)d_in[3];
    const float* W1   = (const float*)d_in[4];
    const float* b1   = (const float*)d_in[5];
    const float* W2   = (const float*)d_in[6];
    const float* b2   = (const float*)d_in[7];
    float* out = (float*)d_out;

    // workspace layout (ws >= 256 MiB; we use ~72 MB)
    char* ws = (char*)d_ws;
    int*      counts = (int*)ws;                        // 256 B
    int*      lists  = (int*)(ws + 256);                // 128 KB
    float*    wts    = (float*)(ws + 256 + 131072);     // 128 KB
    int*      slots  = (int*)(ws + 256 + 262144);       // 32 KB
    ushort_t* W1f    = (ushort_t*)(ws + 256 + 294912);              // 2 MB
    ushort_t* W2f    = (ushort_t*)(ws + 256 + 294912 + 2097152);    // 2 MB
    float*    ybuf   = (float*)(ws + 256 + 294912 + 4194304);       // 67 MB

    zero_counts_kernel<<<1, 64, 0, stream>>>(counts);

    prep_kernel<<<1040, 256, 0, stream>>>(
        x, Wg, bg, bias, W1, W2, W1f, W2f, counts, lists, wts, slots);

    moe_expert_mfma<<<dim3(NUM_EXPERTS, 2, T_TOKENS / TM), 256, 0, stream>>>(
        x, W1f, b1, W2f, b2, counts, lists, wts, ybuf);

    combine_kernel<<<T_TOKENS * 64 / 256, 256, 0, stream>>>(slots, ybuf, out);
}

// Round 6
// 115.934 us; speedup vs baseline: 1.1547x; 1.0106x over previous
//
#include <hip/hip_runtime.h>
#include <hip/hip_bf16.h>
#include <math.h>

#define D_MODEL 256
#define EXPERT_DIM 512
#define NUM_EXPERTS 8
#define T_TOKENS 4096
#define TM 64
#define XS_LD 264    // 256+8 bf16 pad: 528B row (measured 0 conflicts)

typedef unsigned short ushort_t;
typedef short short8_t __attribute__((ext_vector_type(8)));
typedef float f32x4 __attribute__((ext_vector_type(4)));

__device__ __forceinline__ ushort_t f2bf(float f) {
    unsigned int u = __float_as_uint(f);
    u += 0x7FFFu + ((u >> 16) & 1u);   // round-to-nearest-even
    return (ushort_t)(u >> 16);
}

// ---------------------------------------------------------------------------
// Zero the 8 expert counts (ws is poisoned 0xAA before every timed call).
// ---------------------------------------------------------------------------
__global__ void zero_counts_kernel(int* __restrict__ counts)
{
    if (threadIdx.x < NUM_EXPERTS) counts[threadIdx.x] = 0;
}

// ---------------------------------------------------------------------------
// Fused prep.
// Blocks 0..31: gate. 128 tokens/block, 2 threads per token (k-split halves
//   the serial dot), LDS-staged coalesced x reads which ALSO emit xb (bf16 x),
//   LDS histogram -> 8 global atomics/block, writes lists/wts/slots.
// Blocks 32..1055: weight convert fp32 -> bf16 MFMA-fragment order.
// W1f: idx = e<<14 | ntile(5b)<<9 | ks(3b)<<6 | lane   (8 bf16 elems each)
//      element (k,n): n = ntile*16 + (lane&15), k = ks*32 + (lane>>4)*8 + j
// W2f: idx = e<<14 | half<<13 | ntile(4b)<<9 | ks(3b)<<6 | lane
//      element (k,n): n = ntile*16 + l15, k = half*256 + ks*32 + quad*8 + j
// ---------------------------------------------------------------------------
__global__ __launch_bounds__(256) void prep_kernel(
    const float* __restrict__ x, const float* __restrict__ Wg,
    const float* __restrict__ bg, const float* __restrict__ bias,
    const float* __restrict__ W1, const float* __restrict__ W2,
    ushort_t* __restrict__ W1f, ushort_t* __restrict__ W2f,
    ushort_t* __restrict__ xb,
    int* __restrict__ counts, int* __restrict__ lists,
    float* __restrict__ wts, int* __restrict__ slots)
{
    __shared__ float xs[128][33];
    __shared__ float accbuf[128][9];
    __shared__ int lcount[NUM_EXPERTS];
    __shared__ int lbase[NUM_EXPERTS];

    const int tid = threadIdx.x;
    if (blockIdx.x < 32) {
        // ---------------- gate role ----------------
        const int tbase = blockIdx.x * 128;
        const int tl = tid & 127;       // token-local
        const int kh = tid >> 7;        // 0/1 k-half (wave-uniform)
        if (tid < NUM_EXPERTS) lcount[tid] = 0;
        float acc[NUM_EXPERTS];
#pragma unroll
        for (int e = 0; e < NUM_EXPERTS; ++e) acc[e] = 0.f;

        for (int kc = 0; kc < 8; ++kc) {
            __syncthreads();
#pragma unroll
            for (int it = 0; it < 4; ++it) {
                int pos = it * 256 + tid;            // 0..1023
                int r = pos >> 3, c4 = pos & 7;
                const float* src = x + (size_t)(tbase + r) * D_MODEL + kc * 32 + c4 * 4;
                float4 v = *(const float4*)src;
                xs[r][c4 * 4 + 0] = v.x; xs[r][c4 * 4 + 1] = v.y;
                xs[r][c4 * 4 + 2] = v.z; xs[r][c4 * 4 + 3] = v.w;
                ushort4 o;
                o.x = f2bf(v.x); o.y = f2bf(v.y); o.z = f2bf(v.z); o.w = f2bf(v.w);
                *(ushort4*)&xb[(size_t)(tbase + r) * D_MODEL + kc * 32 + c4 * 4] = o;
            }
            __syncthreads();
            for (int k = kh * 16; k < kh * 16 + 16; ++k) {
                float xv = xs[tl][k];
                const float* wr = Wg + (kc * 32 + k) * NUM_EXPERTS;  // wave-uniform
#pragma unroll
                for (int e = 0; e < NUM_EXPERTS; ++e) acc[e] += xv * wr[e];
            }
        }
        __syncthreads();
        if (kh == 1) {
#pragma unroll
            for (int e = 0; e < NUM_EXPERTS; ++e) accbuf[tl][e] = acc[e];
        }
        __syncthreads();
        if (kh == 0) {
            float v0 = -3.0e38f, v1 = -3.0e38f; int i0 = 0, i1 = 0;
#pragma unroll
            for (int e = 0; e < NUM_EXPERTS; ++e) {
                float v = acc[e] + accbuf[tl][e] + bg[e] + bias[e];
                if (v > v0) { v1 = v0; i1 = i0; v0 = v; i0 = e; }
                else if (v > v1) { v1 = v; i1 = e; }
            }
            float e1 = __expf(v1 - v0);
            float inv = 1.f / (1.f + e1);
            float w0 = inv, w1 = e1 * inv;

            int p0 = atomicAdd(&lcount[i0], 1);    // LDS atomics
            int p1 = atomicAdd(&lcount[i1], 1);
            // stash for after the block-wide base allocation
            accbuf[tl][0] = w0; accbuf[tl][1] = w1;
            accbuf[tl][2] = __int_as_float(i0 * T_TOKENS + p0);
            accbuf[tl][3] = __int_as_float(i1 * T_TOKENS + p1);
        }
        __syncthreads();
        if (tid < NUM_EXPERTS) lbase[tid] = atomicAdd(&counts[tid], lcount[tid]);
        __syncthreads();
        if (kh == 0) {
            int t = tbase + tl;
            int s0 = __float_as_int(accbuf[tl][2]);
            int s1 = __float_as_int(accbuf[tl][3]);
            int q0 = s0 % T_TOKENS + lbase[s0 / T_TOKENS];
            int q1 = s1 % T_TOKENS + lbase[s1 / T_TOKENS];
            int i0 = s0 / T_TOKENS, i1 = s1 / T_TOKENS;
            lists[i0 * T_TOKENS + q0] = t;  wts[i0 * T_TOKENS + q0] = accbuf[tl][0];
            lists[i1 * T_TOKENS + q1] = t;  wts[i1 * T_TOKENS + q1] = accbuf[tl][1];
            slots[t * 2 + 0] = i0 * T_TOKENS + q0;
            slots[t * 2 + 1] = i1 * T_TOKENS + q1;
        }
    } else {
        // ---------------- convert role ----------------
        int gid = (blockIdx.x - 32) * 256 + tid;    // 0 .. 262143
        bool isW2 = gid >= 131072;
        int idx = isW2 ? gid - 131072 : gid;
        int lane = idx & 63;
        int l15 = lane & 15, quad = lane >> 4;
        int ks = (idx >> 6) & 7;
        ushort_t o[8];
        if (!isW2) {
            int ntile = (idx >> 9) & 31, e = idx >> 14;
            int nn = ntile * 16 + l15;
            int k0 = ks * 32 + quad * 8;
            const float* s = W1 + ((size_t)e * D_MODEL + k0) * EXPERT_DIM + nn;
#pragma unroll
            for (int j = 0; j < 8; ++j) o[j] = f2bf(s[j * EXPERT_DIM]);
            *(int4*)(W1f + (size_t)idx * 8) = *(int4*)o;
        } else {
            int ntile = (idx >> 9) & 15, half = (idx >> 13) & 1, e = idx >> 14;
            int nn = ntile * 16 + l15;
            int k0 = half * 256 + ks * 32 + quad * 8;
            const float* s = W2 + ((size_t)e * EXPERT_DIM + k0) * D_MODEL + nn;
#pragma unroll
            for (int j = 0; j < 8; ++j) o[j] = f2bf(s[j * D_MODEL]);
            *(int4*)(W2f + (size_t)idx * 8) = *(int4*)o;
        }
    }
}

// ---------------------------------------------------------------------------
// Expert FFN, bf16 MFMA. grid (expert, half, tile64), block 256 = 4 waves.
// TM=64 tokens/tile. Each block: 256-wide half of EXPERT_DIM.
// All 32 B-frags of each stage are loaded UPFRONT (32 concurrent 1KB
// wave-loads -> one L2 latency exposure instead of 8 serial ones), ~128 VGPRs
// of B + 64 of acc; __launch_bounds__(256,2) keeps <=256 VGPR for the
// LDS-capped 2 blocks/CU. Epilogue: plain stores into ybuf (no atomics).
// ---------------------------------------------------------------------------
__global__ __launch_bounds__(256, 2) void moe_expert_mfma(
    const ushort_t* __restrict__ xb,
    const ushort_t* __restrict__ W1f, const float* __restrict__ b1,
    const ushort_t* __restrict__ W2f, const float* __restrict__ b2,
    const int* __restrict__ counts, const int* __restrict__ lists,
    const float* __restrict__ wts, float* __restrict__ ybuf)
{
    const int e = blockIdx.x;
    const int half = blockIdx.y;
    const int n = counts[e];
    const int base = blockIdx.z * TM;
    if (base >= n) return;
    const int m = min(TM, n - base);

    __shared__ ushort_t Xs[TM * XS_LD];   // 33 KB
    __shared__ ushort_t Hs[TM * XS_LD];   // 33 KB (256 cols used)
    __shared__ int   toks[TM];
    __shared__ float wt_s[TM];

    const int tid = threadIdx.x;
    const int lane = tid & 63;
    const int w = tid >> 6;        // wave id: 64-col quarter of this half
    const int l15 = lane & 15;
    const int quad = lane >> 4;

    // ---- stage-1 B: load ALL 32 frags upfront (independent of LDS) ----
    const ushort_t* W1p = W1f + (size_t)(e * 32 + half * 16 + w * 4) * 4096 + lane * 8;
    short8_t b1f[4][8];
#pragma unroll
    for (int nt = 0; nt < 4; ++nt)
#pragma unroll
        for (int ks = 0; ks < 8; ++ks)
            b1f[nt][ks] = *(const short8_t*)(W1p + nt * 4096 + ks * 512);

    if (tid < TM) {
        const int* lst = lists + e * T_TOKENS + base;
        const float* wr = wts + e * T_TOKENS + base;
        toks[tid] = (tid < m) ? lst[tid] : -1;
        wt_s[tid] = (tid < m) ? wr[tid] : 0.f;
    }
    __syncthreads();

    // gather X tile from bf16 xb: 512B per token row, coalesced
    for (int c = tid; c < TM * 32; c += 256) {
        int r = c >> 5, c8 = c & 31;
        int tk = toks[r];
        int4 v = make_int4(0, 0, 0, 0);
        if (tk >= 0) v = *(const int4*)(xb + (size_t)tk * D_MODEL + c8 * 8);
        *(int4*)(Xs + r * XS_LD + c8 * 8) = v;
    }
    __syncthreads();

    // ---------------- stage 1: H = relu(X @ W1[:, half] + b1) --------------
    float b1v[4];
#pragma unroll
    for (int nt = 0; nt < 4; ++nt)
        b1v[nt] = b1[e * EXPERT_DIM + half * 256 + w * 64 + nt * 16 + l15];

    f32x4 acc1[4][4] = {};
    for (int ks = 0; ks < 8; ++ks) {
        short8_t a[4];
#pragma unroll
        for (int mt = 0; mt < 4; ++mt)
            a[mt] = *(const short8_t*)(Xs + (mt * 16 + l15) * XS_LD + ks * 32 + quad * 8);
#pragma unroll
        for (int mt = 0; mt < 4; ++mt)
#pragma unroll
            for (int nt = 0; nt < 4; ++nt)
                acc1[mt][nt] = __builtin_amdgcn_mfma_f32_16x16x32_bf16(
                    a[mt], b1f[nt][ks], acc1[mt][nt], 0, 0, 0);
    }

    // ---- stage-2 B: load ALL 32 frags before the Hs barrier ----
    const ushort_t* W2p = W2f + (size_t)((e * 2 + half) * 16 + w * 4) * 4096 + lane * 8;
    short8_t b2f[4][8];
#pragma unroll
    for (int nt = 0; nt < 4; ++nt)
#pragma unroll
        for (int ks = 0; ks < 8; ++ks)
            b2f[nt][ks] = *(const short8_t*)(W2p + nt * 4096 + ks * 512);
    float b2v[4];
#pragma unroll
    for (int nt = 0; nt < 4; ++nt)
        b2v[nt] = half ? b2[e * D_MODEL + w * 64 + nt * 16 + l15] : 0.f;

    // relu + bias -> Hs (bf16, 256 cols of this half)
#pragma unroll
    for (int mt = 0; mt < 4; ++mt)
#pragma unroll
        for (int nt = 0; nt < 4; ++nt)
#pragma unroll
            for (int r = 0; r < 4; ++r) {
                int row = mt * 16 + quad * 4 + r;
                int col = w * 64 + nt * 16 + l15;
                float h = fmaxf(acc1[mt][nt][r] + b1v[nt], 0.f);
                Hs[row * XS_LD + col] = f2bf(h);
            }
    __syncthreads();

    // ---------------- stage 2: Y = H @ W2[half rows, :] --------------------
    f32x4 acc2[4][4] = {};
    for (int ks = 0; ks < 8; ++ks) {
        short8_t a[4];
#pragma unroll
        for (int mt = 0; mt < 4; ++mt)
            a[mt] = *(const short8_t*)(Hs + (mt * 16 + l15) * XS_LD + ks * 32 + quad * 8);
#pragma unroll
        for (int mt = 0; mt < 4; ++mt)
#pragma unroll
            for (int nt = 0; nt < 4; ++nt)
                acc2[mt][nt] = __builtin_amdgcn_mfma_f32_16x16x32_bf16(
                    a[mt], b2f[nt][ks], acc2[mt][nt], 0, 0, 0);
    }

    // epilogue: plain coalesced stores into ybuf row (half*8+e)*4096 + pos
    float* yrow = ybuf + ((size_t)(half * NUM_EXPERTS + e) * T_TOKENS + base) * D_MODEL;
#pragma unroll
    for (int mt = 0; mt < 4; ++mt)
#pragma unroll
        for (int nt = 0; nt < 4; ++nt)
#pragma unroll
            for (int r = 0; r < 4; ++r) {
                int row = mt * 16 + quad * 4 + r;
                if (row < m) {
                    int col = w * 64 + nt * 16 + l15;
                    yrow[(size_t)row * D_MODEL + col] =
                        wt_s[row] * (acc2[mt][nt][r] + b2v[nt]);
                }
            }
}

// ---------------------------------------------------------------------------
// Combine: out[t] = sum of the 4 ybuf rows for token t (2 experts x 2 halves).
// One wave per token: 4 x 1KB coalesced row reads + 1KB store.
// ---------------------------------------------------------------------------
__global__ __launch_bounds__(256) void combine_kernel(
    const int* __restrict__ slots, const float* __restrict__ ybuf,
    float* __restrict__ out)
{
    int gid = blockIdx.x * 256 + threadIdx.x;   // T_TOKENS * 64 threads
    int t = gid >> 6, lane = gid & 63;
    int s0 = slots[t * 2 + 0];
    int s1 = slots[t * 2 + 1];
    const size_t H = (size_t)NUM_EXPERTS * T_TOKENS * D_MODEL;  // half-bank stride
    float4 a = ((const float4*)(ybuf + (size_t)s0 * D_MODEL))[lane];
    float4 b = ((const float4*)(ybuf + (size_t)s0 * D_MODEL + H))[lane];
    float4 c = ((const float4*)(ybuf + (size_t)s1 * D_MODEL))[lane];
    float4 d = ((const float4*)(ybuf + (size_t)s1 * D_MODEL + H))[lane];
    float4 r;
    r.x = a.x + b.x + c.x + d.x;
    r.y = a.y + b.y + c.y + d.y;
    r.z = a.z + b.z + c.z + d.z;
    r.w = a.w + b.w + c.w + d.w;
    ((float4*)(out + (size_t)t * D_MODEL))[lane] = r;
}

extern "C" void kernel_launch(void* const* d_in, const int* in_sizes, int n_in,
                              void* d_out, int out_size, void* d_ws, size_t ws_size,
                              hipStream_t stream)
{
    const float* x    = (const float*)d_in[0];
    const float* Wg   = (const float*)d_in[1];
    const float* bg   = (const float*)d_in[2];
    const float* bias = (const float*)d_in[3];
    const float* W1   = (const float*)d_in[4];
    const float* b1   = (const float*)d_in[5];
    const float* W2   = (const float*)d_in[6];
    const float* b2   = (const float*)d_in[7];
    float* out = (float*)d_out;

    // workspace layout (~74 MB of the 256 MB ws)
    char* ws = (char*)d_ws;
    int*      counts = (int*)ws;                         // 256 B
    int*      lists  = (int*)(ws + 256);                 // 128 KB
    float*    wts    = (float*)(ws + 131328);            // 128 KB
    int*      slots  = (int*)(ws + 262400);              // 32 KB
    ushort_t* xb     = (ushort_t*)(ws + 524288);         // 2 MB
    ushort_t* W1f    = (ushort_t*)(ws + 2621440);        // 2 MB
    ushort_t* W2f    = (ushort_t*)(ws + 4718592);        // 2 MB
    float*    ybuf   = (float*)(ws + 6815744);           // 64 MB

    zero_counts_kernel<<<1, 64, 0, stream>>>(counts);

    prep_kernel<<<1056, 256, 0, stream>>>(
        x, Wg, bg, bias, W1, W2, W1f, W2f, xb, counts, lists, wts, slots);

    moe_expert_mfma<<<dim3(NUM_EXPERTS, 2, T_TOKENS / TM), 256, 0, stream>>>(
        xb, W1f, b1, W2f, b2, counts, lists, wts, ybuf);

    combine_kernel<<<T_TOKENS * 64 / 256, 256, 0, stream>>>(slots, ybuf, out);
}

// Round 7
// 115.387 us; speedup vs baseline: 1.1601x; 1.0047x over previous
//
#include <hip/hip_runtime.h>
#include <hip/hip_bf16.h>
#include <math.h>

#define D_MODEL 256
#define EXPERT_DIM 512
#define NUM_EXPERTS 8
#define T_TOKENS 4096
#define TM 64
#define NGB 32       // gate blocks (128 tokens each)
#define XS_LD 264    // 256+8 bf16 pad: 528B row (measured 0 conflicts)

typedef unsigned short ushort_t;
typedef short short8_t __attribute__((ext_vector_type(8)));
typedef float f32x4 __attribute__((ext_vector_type(4)));

__device__ __forceinline__ ushort_t f2bf(float f) {
    unsigned int u = __float_as_uint(f);
    u += 0x7FFFu + ((u >> 16) & 1u);   // round-to-nearest-even
    return (ushort_t)(u >> 16);
}

// ---------------------------------------------------------------------------
// Fused prep.
// Blocks 0..31: gate. 128 tokens/block, 2 threads/token (k-split), LDS-staged
//   coalesced x reads that also emit xb (bf16 x). NO global atomics: tokens
//   land in fixed per-(gateblock,expert) segments lists[e*4096+gb*128+lp];
//   per-segment counts -> plain stores to gcounts[gb*8+e]. slots[t] packs
//   both picks as (e<<12|gb<<7|lp) in lo/hi 16 bits.
// Blocks 32..1055: weight convert fp32 -> bf16 MFMA-fragment order.
// W1f: idx = e<<14 | ntile(5b)<<9 | ks(3b)<<6 | lane   (8 bf16 elems each)
// W2f: idx = e<<14 | half<<13 | ntile(4b)<<9 | ks(3b)<<6 | lane
// ---------------------------------------------------------------------------
__global__ __launch_bounds__(256) void prep_kernel(
    const float* __restrict__ x, const float* __restrict__ Wg,
    const float* __restrict__ bg, const float* __restrict__ bias,
    const float* __restrict__ W1, const float* __restrict__ W2,
    ushort_t* __restrict__ W1f, ushort_t* __restrict__ W2f,
    ushort_t* __restrict__ xb,
    int* __restrict__ gcounts, int* __restrict__ lists,
    float* __restrict__ wts, int* __restrict__ slots)
{
    __shared__ float xs[128][33];
    __shared__ float accbuf[128][9];
    __shared__ int lcount[NUM_EXPERTS];

    const int tid = threadIdx.x;
    if (blockIdx.x < NGB) {
        // ---------------- gate role ----------------
        const int gb = blockIdx.x;
        const int tbase = gb * 128;
        const int tl = tid & 127;       // token-local
        const int kh = tid >> 7;        // 0/1 k-half
        if (tid < NUM_EXPERTS) lcount[tid] = 0;
        float acc[NUM_EXPERTS];
#pragma unroll
        for (int e = 0; e < NUM_EXPERTS; ++e) acc[e] = 0.f;

        for (int kc = 0; kc < 8; ++kc) {
            __syncthreads();
#pragma unroll
            for (int it = 0; it < 4; ++it) {
                int pos = it * 256 + tid;            // 0..1023
                int r = pos >> 3, c4 = pos & 7;
                const float* src = x + (size_t)(tbase + r) * D_MODEL + kc * 32 + c4 * 4;
                float4 v = *(const float4*)src;
                xs[r][c4 * 4 + 0] = v.x; xs[r][c4 * 4 + 1] = v.y;
                xs[r][c4 * 4 + 2] = v.z; xs[r][c4 * 4 + 3] = v.w;
                ushort4 o;
                o.x = f2bf(v.x); o.y = f2bf(v.y); o.z = f2bf(v.z); o.w = f2bf(v.w);
                *(ushort4*)&xb[(size_t)(tbase + r) * D_MODEL + kc * 32 + c4 * 4] = o;
            }
            __syncthreads();
            for (int k = kh * 16; k < kh * 16 + 16; ++k) {
                float xv = xs[tl][k];
                const float* wr = Wg + (kc * 32 + k) * NUM_EXPERTS;  // wave-uniform
#pragma unroll
                for (int e = 0; e < NUM_EXPERTS; ++e) acc[e] += xv * wr[e];
            }
        }
        __syncthreads();
        if (kh == 1) {
#pragma unroll
            for (int e = 0; e < NUM_EXPERTS; ++e) accbuf[tl][e] = acc[e];
        }
        __syncthreads();
        if (kh == 0) {
            float v0 = -3.0e38f, v1 = -3.0e38f; int i0 = 0, i1 = 0;
#pragma unroll
            for (int e = 0; e < NUM_EXPERTS; ++e) {
                float v = acc[e] + accbuf[tl][e] + bg[e] + bias[e];
                if (v > v0) { v1 = v0; i1 = i0; v0 = v; i0 = e; }
                else if (v > v1) { v1 = v; i1 = e; }
            }
            float e1 = __expf(v1 - v0);
            float inv = 1.f / (1.f + e1);
            float w0 = inv, w1 = e1 * inv;

            int p0 = atomicAdd(&lcount[i0], 1);    // LDS atomics only
            int p1 = atomicAdd(&lcount[i1], 1);
            int t = tbase + tl;
            lists[i0 * T_TOKENS + gb * 128 + p0] = t;
            wts  [i0 * T_TOKENS + gb * 128 + p0] = w0;
            lists[i1 * T_TOKENS + gb * 128 + p1] = t;
            wts  [i1 * T_TOKENS + gb * 128 + p1] = w1;
            slots[t] = (i0 << 12 | gb << 7 | p0) | ((i1 << 12 | gb << 7 | p1) << 16);
        }
        __syncthreads();
        if (tid < NUM_EXPERTS) gcounts[gb * NUM_EXPERTS + tid] = lcount[tid];
    } else {
        // ---------------- convert role ----------------
        int gid = (blockIdx.x - NGB) * 256 + tid;    // 0 .. 262143
        bool isW2 = gid >= 131072;
        int idx = isW2 ? gid - 131072 : gid;
        int lane = idx & 63;
        int l15 = lane & 15, quad = lane >> 4;
        int ks = (idx >> 6) & 7;
        ushort_t o[8];
        if (!isW2) {
            int ntile = (idx >> 9) & 31, e = idx >> 14;
            int nn = ntile * 16 + l15;
            int k0 = ks * 32 + quad * 8;
            const float* s = W1 + ((size_t)e * D_MODEL + k0) * EXPERT_DIM + nn;
#pragma unroll
            for (int j = 0; j < 8; ++j) o[j] = f2bf(s[j * EXPERT_DIM]);
            *(int4*)(W1f + (size_t)idx * 8) = *(int4*)o;
        } else {
            int ntile = (idx >> 9) & 15, half = (idx >> 13) & 1, e = idx >> 14;
            int nn = ntile * 16 + l15;
            int k0 = half * 256 + ks * 32 + quad * 8;
            const float* s = W2 + ((size_t)e * EXPERT_DIM + k0) * D_MODEL + nn;
#pragma unroll
            for (int j = 0; j < 8; ++j) o[j] = f2bf(s[j * D_MODEL]);
            *(int4*)(W2f + (size_t)idx * 8) = *(int4*)o;
        }
    }
}

// ---------------------------------------------------------------------------
// Expert FFN, bf16 MFMA. grid (expert, half, tile64), block 256 = 4 waves.
// Positions recovered by 32-wide shuffle-scan of gcounts (no global counts).
// Xs and Hs ALIAS one 34 KB LDS buffer (stage2 never needs X) -> with
// streamed depth-1 B prefetch (~130 VGPR) __launch_bounds__(256,3) gives
// 3 blocks/CU = 12 waves/CU (r6 had 8). Plain stores to ybuf, no atomics.
// ---------------------------------------------------------------------------
__global__ __launch_bounds__(256, 3) void moe_expert_mfma(
    const ushort_t* __restrict__ xb,
    const ushort_t* __restrict__ W1f, const float* __restrict__ b1,
    const ushort_t* __restrict__ W2f, const float* __restrict__ b2,
    const int* __restrict__ gcounts, const int* __restrict__ lists,
    const float* __restrict__ wts, float* __restrict__ ybuf)
{
    const int e = blockIdx.x;
    const int half = blockIdx.y;

    __shared__ ushort_t XH[TM * XS_LD];   // 33 KB: Xs, then reused as Hs
    __shared__ int cum[33];
    __shared__ int   toks[TM];
    __shared__ float wt_s[TM];

    const int tid = threadIdx.x;
    // exclusive prefix over the 32 gate-block segments of expert e
    if (tid < 32) {
        int v = gcounts[tid * NUM_EXPERTS + e];
#pragma unroll
        for (int s = 1; s < 32; s <<= 1) {
            int u = __shfl_up(v, s, 32);
            if (tid >= s) v += u;
        }
        cum[tid + 1] = v;
        if (tid == 0) cum[0] = 0;
    }
    __syncthreads();
    const int n = cum[32];
    const int base = blockIdx.z * TM;
    if (base >= n) return;
    const int m = min(TM, n - base);

    const int lane = tid & 63;
    const int w = tid >> 6;        // wave id: 64-col quarter of this half
    const int l15 = lane & 15;
    const int quad = lane >> 4;

    if (tid < TM) {
        int p = base + tid;
        int tk = -1; float wv = 0.f;
        if (p < n) {
            int lo = 0;
#pragma unroll
            for (int s = 16; s >= 1; s >>= 1) if (cum[lo + s] <= p) lo += s;
            int idx = e * T_TOKENS + lo * 128 + (p - cum[lo]);
            tk = lists[idx]; wv = wts[idx];
        }
        toks[tid] = tk; wt_s[tid] = wv;
    }
    __syncthreads();

    // gather X tile from bf16 xb: 512B per token row, coalesced
    for (int c = tid; c < TM * 32; c += 256) {
        int r = c >> 5, c8 = c & 31;
        int tk = toks[r];
        int4 v = make_int4(0, 0, 0, 0);
        if (tk >= 0) v = *(const int4*)(xb + (size_t)tk * D_MODEL + c8 * 8);
        *(int4*)(XH + r * XS_LD + c8 * 8) = v;
    }
    __syncthreads();

    // ---------------- stage 1: H = relu(X @ W1[:, half] + b1) --------------
    const ushort_t* W1p = W1f + (size_t)(e * 32 + half * 16 + w * 4) * 4096 + lane * 8;
    float b1v[4];
#pragma unroll
    for (int nt = 0; nt < 4; ++nt)
        b1v[nt] = b1[e * EXPERT_DIM + half * 256 + w * 64 + nt * 16 + l15];

    f32x4 acc1[4][4] = {};
    short8_t bc[4];
#pragma unroll
    for (int nt = 0; nt < 4; ++nt) bc[nt] = *(const short8_t*)(W1p + nt * 4096);

    for (int ks = 0; ks < 8; ++ks) {
        short8_t bn[4];
        if (ks < 7) {
#pragma unroll
            for (int nt = 0; nt < 4; ++nt)
                bn[nt] = *(const short8_t*)(W1p + nt * 4096 + (ks + 1) * 512);
        }
        short8_t a[4];
#pragma unroll
        for (int mt = 0; mt < 4; ++mt)
            a[mt] = *(const short8_t*)(XH + (mt * 16 + l15) * XS_LD + ks * 32 + quad * 8);
#pragma unroll
        for (int mt = 0; mt < 4; ++mt)
#pragma unroll
            for (int nt = 0; nt < 4; ++nt)
                acc1[mt][nt] = __builtin_amdgcn_mfma_f32_16x16x32_bf16(
                    a[mt], bc[nt], acc1[mt][nt], 0, 0, 0);
        if (ks < 7) {
#pragma unroll
            for (int nt = 0; nt < 4; ++nt) bc[nt] = bn[nt];
        }
    }

    // stage-2 B first frags prefetch + b2 before the barrier
    const ushort_t* W2p = W2f + (size_t)((e * 2 + half) * 16 + w * 4) * 4096 + lane * 8;
    short8_t bc2[4];
#pragma unroll
    for (int nt = 0; nt < 4; ++nt) bc2[nt] = *(const short8_t*)(W2p + nt * 4096);
    float b2v[4];
#pragma unroll
    for (int nt = 0; nt < 4; ++nt)
        b2v[nt] = half ? b2[e * D_MODEL + w * 64 + nt * 16 + l15] : 0.f;

    __syncthreads();   // all stage-1 X reads done; XH becomes Hs
#pragma unroll
    for (int mt = 0; mt < 4; ++mt)
#pragma unroll
        for (int nt = 0; nt < 4; ++nt)
#pragma unroll
            for (int r = 0; r < 4; ++r) {
                int row = mt * 16 + quad * 4 + r;
                int col = w * 64 + nt * 16 + l15;
                float h = fmaxf(acc1[mt][nt][r] + b1v[nt], 0.f);
                XH[row * XS_LD + col] = f2bf(h);
            }
    __syncthreads();

    // ---------------- stage 2: Y = H @ W2[half rows, :] --------------------
    f32x4 acc2[4][4] = {};
    for (int ks = 0; ks < 8; ++ks) {
        short8_t bn2[4];
        if (ks < 7) {
#pragma unroll
            for (int nt = 0; nt < 4; ++nt)
                bn2[nt] = *(const short8_t*)(W2p + nt * 4096 + (ks + 1) * 512);
        }
        short8_t a[4];
#pragma unroll
        for (int mt = 0; mt < 4; ++mt)
            a[mt] = *(const short8_t*)(XH + (mt * 16 + l15) * XS_LD + ks * 32 + quad * 8);
#pragma unroll
        for (int mt = 0; mt < 4; ++mt)
#pragma unroll
            for (int nt = 0; nt < 4; ++nt)
                acc2[mt][nt] = __builtin_amdgcn_mfma_f32_16x16x32_bf16(
                    a[mt], bc2[nt], acc2[mt][nt], 0, 0, 0);
        if (ks < 7) {
#pragma unroll
            for (int nt = 0; nt < 4; ++nt) bc2[nt] = bn2[nt];
        }
    }

    // epilogue: plain coalesced stores into ybuf row (half*8+e)*4096 + p
    float* yrow = ybuf + ((size_t)(half * NUM_EXPERTS + e) * T_TOKENS + base) * D_MODEL;
#pragma unroll
    for (int mt = 0; mt < 4; ++mt)
#pragma unroll
        for (int nt = 0; nt < 4; ++nt)
#pragma unroll
            for (int r = 0; r < 4; ++r) {
                int row = mt * 16 + quad * 4 + r;
                if (row < m) {
                    int col = w * 64 + nt * 16 + l15;
                    yrow[(size_t)row * D_MODEL + col] =
                        wt_s[row] * (acc2[mt][nt][r] + b2v[nt]);
                }
            }
}

// ---------------------------------------------------------------------------
// Combine: out[t] = sum of 4 ybuf rows (2 experts x 2 halves). Positions
// recovered via per-expert shuffle-scan of gcounts (waves 0..3 handle two
// experts each). One wave per token: 4 x 1KB reads + 1KB store.
// ---------------------------------------------------------------------------
__global__ __launch_bounds__(256) void combine_kernel(
    const int* __restrict__ slots, const int* __restrict__ gcounts,
    const float* __restrict__ ybuf, float* __restrict__ out)
{
    __shared__ int cum8[NUM_EXPERTS][33];
    const int tid = threadIdx.x;
    const int lane = tid & 63;
    const int wv = tid >> 6;
    if (lane < 32) {
#pragma unroll
        for (int rpt = 0; rpt < 2; ++rpt) {
            int e = wv + rpt * 4;
            int v = gcounts[lane * NUM_EXPERTS + e];
#pragma unroll
            for (int s = 1; s < 32; s <<= 1) {
                int u = __shfl_up(v, s, 32);
                if (lane >= s) v += u;
            }
            cum8[e][lane + 1] = v;
            if (lane == 0) cum8[e][0] = 0;
        }
    }
    __syncthreads();

    int gid = blockIdx.x * 256 + tid;   // T_TOKENS * 64 threads
    int t = gid >> 6;
    int sl = slots[t];
    int s0 = sl & 0xFFFF, s1 = (sl >> 16) & 0xFFFF;
    int e0 = s0 >> 12, gb0 = (s0 >> 7) & 31, lp0 = s0 & 127;
    int e1 = s1 >> 12, gb1 = (s1 >> 7) & 31, lp1 = s1 & 127;
    int p0 = cum8[e0][gb0] + lp0;
    int p1 = cum8[e1][gb1] + lp1;
    const size_t H = (size_t)NUM_EXPERTS * T_TOKENS * D_MODEL;  // half stride
    const float4* r0 = (const float4*)(ybuf + ((size_t)e0 * T_TOKENS + p0) * D_MODEL);
    const float4* r1 = (const float4*)(ybuf + ((size_t)e1 * T_TOKENS + p1) * D_MODEL);
    float4 a = r0[lane];
    float4 b = *(const float4*)((const float*)(r0) + H + lane * 4);
    float4 c = r1[lane];
    float4 d = *(const float4*)((const float*)(r1) + H + lane * 4);
    float4 r;
    r.x = a.x + b.x + c.x + d.x;
    r.y = a.y + b.y + c.y + d.y;
    r.z = a.z + b.z + c.z + d.z;
    r.w = a.w + b.w + c.w + d.w;
    ((float4*)(out + (size_t)t * D_MODEL))[lane] = r;
}

extern "C" void kernel_launch(void* const* d_in, const int* in_sizes, int n_in,
                              void* d_out, int out_size, void* d_ws, size_t ws_size,
                              hipStream_t stream)
{
    const float* x    = (const float*)d_in[0];
    const float* Wg   = (const float*)d_in[1];
    const float* bg   = (const float*)d_in[2];
    const float* bias = (const float*)d_in[3];
    const float* W1   = (const float*)d_in[4];
    const float* b1   = (const float*)d_in[5];
    const float* W2   = (const float*)d_in[6];
    const float* b2   = (const float*)d_in[7];
    float* out = (float*)d_out;

    // workspace layout (~71 MB of the 256 MB ws)
    char* ws = (char*)d_ws;
    int*      gcounts = (int*)ws;                        // 1 KB (256 ints)
    int*      lists   = (int*)(ws + 1024);               // 128 KB
    float*    wts     = (float*)(ws + 132096);           // 128 KB
    int*      slots   = (int*)(ws + 263168);             // 16 KB
    ushort_t* xb      = (ushort_t*)(ws + 524288);        // 2 MB
    ushort_t* W1f     = (ushort_t*)(ws + 2621440);       // 2 MB
    ushort_t* W2f     = (ushort_t*)(ws + 4718592);       // 2 MB
    float*    ybuf    = (float*)(ws + 6815744);          // 64 MB

    prep_kernel<<<1056, 256, 0, stream>>>(
        x, Wg, bg, bias, W1, W2, W1f, W2f, xb, gcounts, lists, wts, slots);

    moe_expert_mfma<<<dim3(NUM_EXPERTS, 2, T_TOKENS / TM), 256, 0, stream>>>(
        xb, W1f, b1, W2f, b2, gcounts, lists, wts, ybuf);

    combine_kernel<<<T_TOKENS * 64 / 256, 256, 0, stream>>>(slots, gcounts, ybuf, out);
}

// Round 8
// 104.554 us; speedup vs baseline: 1.2803x; 1.1036x over previous
//
#include <hip/hip_runtime.h>
#include <hip/hip_bf16.h>
#include <math.h>

#define D_MODEL 256
#define EXPERT_DIM 512
#define NUM_EXPERTS 8
#define T_TOKENS 4096
#define TM 64
#define NGB 256      // gate blocks (16 tokens each)
#define XS_LD 264    // 256+8 bf16 pad: 528B row (measured 0 conflicts)

typedef unsigned short ushort_t;
typedef short short8_t __attribute__((ext_vector_type(8)));
typedef float f32x4 __attribute__((ext_vector_type(4)));

__device__ __forceinline__ ushort_t f2bf(float f) {
    unsigned int u = __float_as_uint(f);
    u += 0x7FFFu + ((u >> 16) & 1u);   // round-to-nearest-even
    return (ushort_t)(u >> 16);
}
__device__ __forceinline__ float bf2f(ushort_t u) {
    return __uint_as_float((unsigned int)u << 16);
}

// ---------------------------------------------------------------------------
// Fused prep.
// Blocks 0..255: gate. 16 tokens/block, 16 threads/token. x row kept in
//   registers (no LDS), Wg read direct (L1-broadcast across the 16 dup
//   threads), 16-lane shuffle reduction, top-2 + softmax by leader lane.
//   Tokens land in fixed per-(seg,expert) segments of width 16:
//   lists[e*4096 + seg*16 + lp]; counts -> plain stores gcounts[seg*8+e].
//   slots[t] packs (e<<12 | seg<<4 | lp) per pick in lo/hi 16 bits.
// Blocks 256..1279: weight convert fp32 -> bf16 MFMA-fragment order.
// W1f: idx = e<<14 | ntile(5b)<<9 | ks(3b)<<6 | lane   (8 bf16 elems each)
// W2f: idx = e<<14 | half<<13 | ntile(4b)<<9 | ks(3b)<<6 | lane
// ---------------------------------------------------------------------------
__global__ __launch_bounds__(256) void prep_kernel(
    const float* __restrict__ x, const float* __restrict__ Wg,
    const float* __restrict__ bg, const float* __restrict__ bias,
    const float* __restrict__ W1, const float* __restrict__ W2,
    ushort_t* __restrict__ W1f, ushort_t* __restrict__ W2f,
    ushort_t* __restrict__ xb,
    int* __restrict__ gcounts, int* __restrict__ lists,
    float* __restrict__ wts, int* __restrict__ slots)
{
    __shared__ int lcount[NUM_EXPERTS];
    const int tid = threadIdx.x;

    if (blockIdx.x < NGB) {
        // ---------------- gate role ----------------
        const int gb = blockIdx.x;
        const int r = tid >> 4;        // token 0..15
        const int c = tid & 15;        // k-chunk 0..15 (16 k each)
        const int t = gb * 16 + r;
        if (tid < NUM_EXPERTS) lcount[tid] = 0;

        // load 16 x values (64B per thread, coalesced across c)
        float xr[16];
        const float4* xp = (const float4*)(x + (size_t)t * D_MODEL + c * 16);
#pragma unroll
        for (int q = 0; q < 4; ++q) {
            float4 v = xp[q];
            xr[q * 4 + 0] = v.x; xr[q * 4 + 1] = v.y;
            xr[q * 4 + 2] = v.z; xr[q * 4 + 3] = v.w;
        }
        // emit bf16 x (32B per thread, coalesced)
        ushort_t o16[16];
#pragma unroll
        for (int j = 0; j < 16; ++j) o16[j] = f2bf(xr[j]);
        ushort_t* xbp = xb + (size_t)t * D_MODEL + c * 16;
        *(int4*)(xbp)     = *(int4*)(o16);
        *(int4*)(xbp + 8) = *(int4*)(o16 + 8);

        // partial gate logits over this thread's 16 k
        float acc[NUM_EXPERTS];
#pragma unroll
        for (int e = 0; e < NUM_EXPERTS; ++e) acc[e] = 0.f;
#pragma unroll
        for (int j = 0; j < 16; ++j) {
            const float4* wg = (const float4*)(Wg + (c * 16 + j) * NUM_EXPERTS);
            float4 w0 = wg[0], w1 = wg[1];
            float xv = xr[j];
            acc[0] += xv * w0.x; acc[1] += xv * w0.y;
            acc[2] += xv * w0.z; acc[3] += xv * w0.w;
            acc[4] += xv * w1.x; acc[5] += xv * w1.y;
            acc[6] += xv * w1.z; acc[7] += xv * w1.w;
        }
        // reduce across the 16 lanes of this token (xor masks stay in group)
#pragma unroll
        for (int e = 0; e < NUM_EXPERTS; ++e) {
#pragma unroll
            for (int s = 1; s < 16; s <<= 1) acc[e] += __shfl_xor(acc[e], s);
        }
        __syncthreads();
        if (c == 0) {
            float v0 = -3.0e38f, v1 = -3.0e38f; int i0 = 0, i1 = 0;
#pragma unroll
            for (int e = 0; e < NUM_EXPERTS; ++e) {
                float v = acc[e] + bg[e] + bias[e];
                if (v > v0) { v1 = v0; i1 = i0; v0 = v; i0 = e; }
                else if (v > v1) { v1 = v; i1 = e; }
            }
            float e1 = __expf(v1 - v0);
            float inv = 1.f / (1.f + e1);
            float w0 = inv, w1 = e1 * inv;

            int p0 = atomicAdd(&lcount[i0], 1);    // LDS atomics only
            int p1 = atomicAdd(&lcount[i1], 1);
            lists[i0 * T_TOKENS + gb * 16 + p0] = t;
            wts  [i0 * T_TOKENS + gb * 16 + p0] = w0;
            lists[i1 * T_TOKENS + gb * 16 + p1] = t;
            wts  [i1 * T_TOKENS + gb * 16 + p1] = w1;
            slots[t] = (i0 << 12 | gb << 4 | p0) | ((i1 << 12 | gb << 4 | p1) << 16);
        }
        __syncthreads();
        if (tid < NUM_EXPERTS) gcounts[gb * NUM_EXPERTS + tid] = lcount[tid];
    } else {
        // ---------------- convert role ----------------
        int gid = (blockIdx.x - NGB) * 256 + tid;    // 0 .. 262143
        bool isW2 = gid >= 131072;
        int idx = isW2 ? gid - 131072 : gid;
        int lane = idx & 63;
        int l15 = lane & 15, quad = lane >> 4;
        int ks = (idx >> 6) & 7;
        ushort_t o[8];
        if (!isW2) {
            int ntile = (idx >> 9) & 31, e = idx >> 14;
            int nn = ntile * 16 + l15;
            int k0 = ks * 32 + quad * 8;
            const float* s = W1 + ((size_t)e * D_MODEL + k0) * EXPERT_DIM + nn;
#pragma unroll
            for (int j = 0; j < 8; ++j) o[j] = f2bf(s[j * EXPERT_DIM]);
            *(int4*)(W1f + (size_t)idx * 8) = *(int4*)o;
        } else {
            int ntile = (idx >> 9) & 15, half = (idx >> 13) & 1, e = idx >> 14;
            int nn = ntile * 16 + l15;
            int k0 = half * 256 + ks * 32 + quad * 8;
            const float* s = W2 + ((size_t)e * EXPERT_DIM + k0) * D_MODEL + nn;
#pragma unroll
            for (int j = 0; j < 8; ++j) o[j] = f2bf(s[j * D_MODEL]);
            *(int4*)(W2f + (size_t)idx * 8) = *(int4*)o;
        }
    }
}

// ---------------------------------------------------------------------------
// Expert FFN, bf16 MFMA. grid (expert, half, tile64), block 256 = 4 waves.
// Positions via 256-wide block scan of gcounts. Xs/Hs alias one 33 KB LDS
// buffer; streamed depth-1 B prefetch; plain bf16 stores to ybuf.
// ---------------------------------------------------------------------------
__global__ __launch_bounds__(256, 3) void moe_expert_mfma(
    const ushort_t* __restrict__ xb,
    const ushort_t* __restrict__ W1f, const float* __restrict__ b1,
    const ushort_t* __restrict__ W2f, const float* __restrict__ b2,
    const int* __restrict__ gcounts, const int* __restrict__ lists,
    const float* __restrict__ wts, ushort_t* __restrict__ ybuf)
{
    const int e = blockIdx.x;
    const int half = blockIdx.y;

    __shared__ ushort_t XH[TM * XS_LD];   // 33 KB: Xs, then reused as Hs
    __shared__ int cum[257];
    __shared__ int wsums[4];
    __shared__ int   toks[TM];
    __shared__ float wt_s[TM];

    const int tid = threadIdx.x;
    const int lane = tid & 63;
    const int w = tid >> 6;
    const int l15 = lane & 15;
    const int quad = lane >> 4;

    // block-wide exclusive prefix over the 256 gate segments of expert e
    {
        int v = gcounts[tid * NUM_EXPERTS + e];
#pragma unroll
        for (int s = 1; s < 64; s <<= 1) {
            int u = __shfl_up(v, s);
            if (lane >= s) v += u;
        }
        if (lane == 63) wsums[w] = v;
        __syncthreads();
        int off = 0;
        for (int i = 0; i < w; ++i) off += wsums[i];
        cum[tid + 1] = v + off;
        if (tid == 0) cum[0] = 0;
        __syncthreads();
    }
    const int n = cum[256];
    const int base = blockIdx.z * TM;
    if (base >= n) return;
    const int m = min(TM, n - base);

    if (tid < TM) {
        int p = base + tid;
        int tk = -1; float wv = 0.f;
        if (p < n) {
            int lo = 0;
#pragma unroll
            for (int s = 128; s >= 1; s >>= 1)
                if (cum[lo + s] <= p) lo += s;
            int idx = e * T_TOKENS + lo * 16 + (p - cum[lo]);
            tk = lists[idx]; wv = wts[idx];
        }
        toks[tid] = tk; wt_s[tid] = wv;
    }
    __syncthreads();

    // gather X tile from bf16 xb: 512B per token row, coalesced
    for (int c = tid; c < TM * 32; c += 256) {
        int r = c >> 5, c8 = c & 31;
        int tk = toks[r];
        int4 v = make_int4(0, 0, 0, 0);
        if (tk >= 0) v = *(const int4*)(xb + (size_t)tk * D_MODEL + c8 * 8);
        *(int4*)(XH + r * XS_LD + c8 * 8) = v;
    }
    __syncthreads();

    // ---------------- stage 1: H = relu(X @ W1[:, half] + b1) --------------
    const ushort_t* W1p = W1f + (size_t)(e * 32 + half * 16 + w * 4) * 4096 + lane * 8;
    float b1v[4];
#pragma unroll
    for (int nt = 0; nt < 4; ++nt)
        b1v[nt] = b1[e * EXPERT_DIM + half * 256 + w * 64 + nt * 16 + l15];

    f32x4 acc1[4][4] = {};
    short8_t bc[4];
#pragma unroll
    for (int nt = 0; nt < 4; ++nt) bc[nt] = *(const short8_t*)(W1p + nt * 4096);

    for (int ks = 0; ks < 8; ++ks) {
        short8_t bn[4];
        if (ks < 7) {
#pragma unroll
            for (int nt = 0; nt < 4; ++nt)
                bn[nt] = *(const short8_t*)(W1p + nt * 4096 + (ks + 1) * 512);
        }
        short8_t a[4];
#pragma unroll
        for (int mt = 0; mt < 4; ++mt)
            a[mt] = *(const short8_t*)(XH + (mt * 16 + l15) * XS_LD + ks * 32 + quad * 8);
#pragma unroll
        for (int mt = 0; mt < 4; ++mt)
#pragma unroll
            for (int nt = 0; nt < 4; ++nt)
                acc1[mt][nt] = __builtin_amdgcn_mfma_f32_16x16x32_bf16(
                    a[mt], bc[nt], acc1[mt][nt], 0, 0, 0);
        if (ks < 7) {
#pragma unroll
            for (int nt = 0; nt < 4; ++nt) bc[nt] = bn[nt];
        }
    }

    // stage-2 B first frags + b2 prefetch before the barrier
    const ushort_t* W2p = W2f + (size_t)((e * 2 + half) * 16 + w * 4) * 4096 + lane * 8;
    short8_t bc2[4];
#pragma unroll
    for (int nt = 0; nt < 4; ++nt) bc2[nt] = *(const short8_t*)(W2p + nt * 4096);
    float b2v[4];
#pragma unroll
    for (int nt = 0; nt < 4; ++nt)
        b2v[nt] = half ? b2[e * D_MODEL + w * 64 + nt * 16 + l15] : 0.f;

    __syncthreads();   // all stage-1 X reads done; XH becomes Hs
#pragma unroll
    for (int mt = 0; mt < 4; ++mt)
#pragma unroll
        for (int nt = 0; nt < 4; ++nt)
#pragma unroll
            for (int r = 0; r < 4; ++r) {
                int row = mt * 16 + quad * 4 + r;
                int col = w * 64 + nt * 16 + l15;
                float h = fmaxf(acc1[mt][nt][r] + b1v[nt], 0.f);
                XH[row * XS_LD + col] = f2bf(h);
            }
    __syncthreads();

    // ---------------- stage 2: Y = H @ W2[half rows, :] --------------------
    f32x4 acc2[4][4] = {};
    for (int ks = 0; ks < 8; ++ks) {
        short8_t bn2[4];
        if (ks < 7) {
#pragma unroll
            for (int nt = 0; nt < 4; ++nt)
                bn2[nt] = *(const short8_t*)(W2p + nt * 4096 + (ks + 1) * 512);
        }
        short8_t a[4];
#pragma unroll
        for (int mt = 0; mt < 4; ++mt)
            a[mt] = *(const short8_t*)(XH + (mt * 16 + l15) * XS_LD + ks * 32 + quad * 8);
#pragma unroll
        for (int mt = 0; mt < 4; ++mt)
#pragma unroll
            for (int nt = 0; nt < 4; ++nt)
                acc2[mt][nt] = __builtin_amdgcn_mfma_f32_16x16x32_bf16(
                    a[mt], bc2[nt], acc2[mt][nt], 0, 0, 0);
        if (ks < 7) {
#pragma unroll
            for (int nt = 0; nt < 4; ++nt) bc2[nt] = bn2[nt];
        }
    }

    // epilogue: bf16 stores into ybuf row (half*8+e)*4096 + p  (no atomics)
    ushort_t* yrow = ybuf + ((size_t)(half * NUM_EXPERTS + e) * T_TOKENS + base) * D_MODEL;
#pragma unroll
    for (int mt = 0; mt < 4; ++mt)
#pragma unroll
        for (int nt = 0; nt < 4; ++nt)
#pragma unroll
            for (int r = 0; r < 4; ++r) {
                int row = mt * 16 + quad * 4 + r;
                if (row < m) {
                    int col = w * 64 + nt * 16 + l15;
                    yrow[(size_t)row * D_MODEL + col] =
                        f2bf(wt_s[row] * (acc2[mt][nt][r] + b2v[nt]));
                }
            }
}

// ---------------------------------------------------------------------------
// Combine: out[t] = sum of 4 bf16 ybuf rows (2 experts x 2 halves).
// Per-expert 256-seg prefix recomputed per block (wave-chunked scan).
// One wave per token: 4 x 512B reads + 1KB fp32 store.
// ---------------------------------------------------------------------------
__global__ __launch_bounds__(256) void combine_kernel(
    const int* __restrict__ slots, const int* __restrict__ gcounts,
    const ushort_t* __restrict__ ybuf, float* __restrict__ out)
{
    __shared__ int cum8[NUM_EXPERTS][257];
    const int tid = threadIdx.x;
    const int lane = tid & 63;
    const int wv = tid >> 6;
#pragma unroll
    for (int rpt = 0; rpt < 2; ++rpt) {
        int e = wv + rpt * 4;
        int carry = 0;
        for (int ch = 0; ch < 4; ++ch) {
            int v = gcounts[(ch * 64 + lane) * NUM_EXPERTS + e];
#pragma unroll
            for (int s = 1; s < 64; s <<= 1) {
                int u = __shfl_up(v, s);
                if (lane >= s) v += u;
            }
            v += carry;
            cum8[e][ch * 64 + lane + 1] = v;
            carry = __shfl(v, 63);
        }
        if (lane == 0) cum8[e][0] = 0;
    }
    __syncthreads();

    int gid = blockIdx.x * 256 + tid;   // T_TOKENS * 64 threads
    int t = gid >> 6;
    int sl = slots[t];
    int s0 = sl & 0xFFFF, s1 = (sl >> 16) & 0xFFFF;
    int e0 = (s0 >> 12) & 7, g0 = (s0 >> 4) & 255, lp0 = s0 & 15;
    int e1 = (s1 >> 12) & 7, g1 = (s1 >> 4) & 255, lp1 = s1 & 15;
    int p0 = cum8[e0][g0] + lp0;
    int p1 = cum8[e1][g1] + lp1;
    const size_t H = (size_t)NUM_EXPERTS * T_TOKENS * D_MODEL;  // half stride
    size_t o0 = ((size_t)e0 * T_TOKENS + p0) * D_MODEL + lane * 4;
    size_t o1 = ((size_t)e1 * T_TOKENS + p1) * D_MODEL + lane * 4;
    ushort4 a = *(const ushort4*)(ybuf + o0);
    ushort4 b = *(const ushort4*)(ybuf + o0 + H);
    ushort4 c = *(const ushort4*)(ybuf + o1);
    ushort4 d = *(const ushort4*)(ybuf + o1 + H);
    float4 r;
    r.x = bf2f(a.x) + bf2f(b.x) + bf2f(c.x) + bf2f(d.x);
    r.y = bf2f(a.y) + bf2f(b.y) + bf2f(c.y) + bf2f(d.y);
    r.z = bf2f(a.z) + bf2f(b.z) + bf2f(c.z) + bf2f(d.z);
    r.w = bf2f(a.w) + bf2f(b.w) + bf2f(c.w) + bf2f(d.w);
    *(float4*)(out + (size_t)t * D_MODEL + lane * 4) = r;
}

extern "C" void kernel_launch(void* const* d_in, const int* in_sizes, int n_in,
                              void* d_out, int out_size, void* d_ws, size_t ws_size,
                              hipStream_t stream)
{
    const float* x    = (const float*)d_in[0];
    const float* Wg   = (const float*)d_in[1];
    const float* bg   = (const float*)d_in[2];
    const float* bias = (const float*)d_in[3];
    const float* W1   = (const float*)d_in[4];
    const float* b1   = (const float*)d_in[5];
    const float* W2   = (const float*)d_in[6];
    const float* b2   = (const float*)d_in[7];
    float* out = (float*)d_out;

    // workspace layout (~40 MB of the 256 MB ws)
    char* ws = (char*)d_ws;
    int*      gcounts = (int*)ws;                        // 8 KB (2048 ints)
    int*      lists   = (int*)(ws + 8192);               // 128 KB
    float*    wts     = (float*)(ws + 139264);           // 128 KB
    int*      slots   = (int*)(ws + 270336);             // 16 KB
    ushort_t* xb      = (ushort_t*)(ws + 524288);        // 2 MB
    ushort_t* W1f     = (ushort_t*)(ws + 2621440);       // 2 MB
    ushort_t* W2f     = (ushort_t*)(ws + 4718592);       // 2 MB
    ushort_t* ybuf    = (ushort_t*)(ws + 6815744);       // 33.5 MB (bf16)

    prep_kernel<<<NGB + 1024, 256, 0, stream>>>(
        x, Wg, bg, bias, W1, W2, W1f, W2f, xb, gcounts, lists, wts, slots);

    moe_expert_mfma<<<dim3(NUM_EXPERTS, 2, T_TOKENS / TM), 256, 0, stream>>>(
        xb, W1f, b1, W2f, b2, gcounts, lists, wts, ybuf);

    combine_kernel<<<T_TOKENS * 64 / 256, 256, 0, stream>>>(slots, gcounts, ybuf, out);
}